// Round 7
// baseline (267.977 us; speedup 1.0000x reference)
//
#include <hip/hip_runtime.h>
#include <hip/hip_bf16.h>

// ---------------------------------------------------------------------------
// MessagePassingModel: N=10000 atoms, E=160000 edges, NC=9 SH channels,
// F=32 features, NB=16 radial basis, NITER=3.
// History: R17 @212 (8 dispatches). R18 coop @972 (grid.sync L2 storm).
// R19 tile-fused @372 (occupancy 6.6%). R20 @224 / R22 @236 / R23 @223:
// iter kernel stuck at ~59-75us. R23 counters: VALU 30%, HBM 10%, Occ 30%
// -> ~18us issue + ~40us unhidden latency; per-edge serial chain
// (sidx -> x[s], depth-1 prefetch) + low residency can't hide HBM misses
// (caches invalidated at every dispatch boundary -> ~20MB/iter compulsory).
// R24: batched-MLP gather. Blocked half-split (half's edges contiguous);
// load up to 4 sidx at once, then ALL <=36 x[s] plane loads issue
// concurrently before compute -> gather latency ~2 flat trips regardless of
// degree. Residual xr loads hoisted above gather. Dense/readout unchanged.
// ---------------------------------------------------------------------------

#define NITER 3
#define BCAP  64      // bucket capacity; post-cutoff dst degree ~Poisson(2.7),
                      // P(>64) ~ 0; dataset fixed -> safe.

// wcvt (fp32 converted weights) layout offsets, in floats
#define OFF_WB    0        // [NITER][3][16][32] = 4608
#define OFF_W1    4608     // [NITER][3][32][32] = 9216
#define OFF_B1    13824    // [NITER][32] = 96
#define OFF_W2    13920    // 9216
#define OFF_B2    23136    // 96
#define OFF_WT00  23232    // [32][4] = 128
#define OFF_WT11  23360    // 128
#define OFF_WMONO 23488    // [4][4] = 16
#define OFF_EB    23504    // 18
#define OFF_EMB   23522    // [18][32] = 576
#define WC_TOTAL  24098

__device__ __forceinline__ float b2f(const __hip_bfloat16 v) { return __bfloat162float(v); }

// Analytic real-Gaunt coefficients for l<=2:
#define KC0 0.28209479177387814f
#define KG1 0.21850968611841584f
#define KG2 0.12615662610100802f
#define KG3 0.18022375157287861f
#define KG4 0.09011187578643931f
#define KG5 0.15607834722743988f

__device__ __forceinline__ float ldany(const void* p, int i, bool f32) {
    return f32 ? ((const float*)p)[i] : b2f(((const __hip_bfloat16*)p)[i]);
}

// Per-wave dtype sniff (fp32-read-as-bf16 -> huge/NaN with ~43%/sample).
__device__ __forceinline__ bool wave_sniff(const void* pos) {
    const __hip_bfloat16* p = (const __hip_bfloat16*)pos;
    int lane = threadIdx.x & 63;
    int bad = 0;
    #pragma unroll
    for (int k = 0; k < 4; k++) {
        float v = b2f(p[lane + k*64]);
        bad |= !(fabsf(v) < 1.0e6f);
    }
    return __ballot(bad) != 0ull;
}

__device__ __forceinline__ float xadd32(float v) {   // v += lane^32 partner
    return v + __int_as_float(__shfl_xor(__float_as_int(v), 32, 64));
}

// --- geometry helper --------------------------------------------------------
__device__ __forceinline__ bool edge_geom(float dx, float dy, float dz,
                                          float* sp, float* rad) {
    float r2 = dx*dx + dy*dy + dz*dz + 1e-12f;
    if (r2 >= 16.0f) return false;
    float r  = sqrtf(r2);
    float t2 = r2 * 0.0625f;
    float fc = __expf(-t2 / (1.0f - t2));
    float u = 1.0f / (1.0f + r);
    float v = 1.0f - u;
    const float BIN[16] = {1.f,15.f,105.f,455.f,1365.f,3003.f,5005.f,6435.f,
                           6435.f,5005.f,3003.f,1365.f,455.f,105.f,15.f,1.f};
    float vp[16];
    vp[0] = 1.0f;
    #pragma unroll
    for (int k = 1; k < 16; k++) vp[k] = vp[k-1] * v;
    float up = 1.0f;
    #pragma unroll
    for (int n = 0; n < 16; n++) { rad[n] = BIN[n] * up * vp[15-n] * fc; up *= u; }
    float ir = 1.0f / r;
    float ux = dx*ir, uy = dy*ir, uz = dz*ir;
    const float c0 = 0.28209479177387814f, c1 = 0.4886025119029199f;
    const float c2a = 1.0925484305920792f, c2b = 0.31539156525252005f, c2c = 0.5462742152960396f;
    sp[0] = c0;
    sp[1] = c1*uy; sp[2] = c1*uz; sp[3] = c1*ux;
    sp[4] = c2a*ux*uy; sp[5] = c2a*uy*uz; sp[6] = c2b*(3.0f*uz*uz - 1.0f);
    sp[7] = c2a*ux*uz; sp[8] = c2c*(ux*ux - uy*uy);
    return true;
}

// --- geo2 slot writer (layout: sph[0..8] pad[9..15] rad[16..31]) ------------
__device__ __forceinline__ void write_geo_slot(float* gp,
                                               const float* sp, const float* rad) {
    float4* g4 = (float4*)gp;                     // geo2 is 128B-aligned
    g4[0] = make_float4(sp[0], sp[1], sp[2], sp[3]);
    g4[1] = make_float4(sp[4], sp[5], sp[6], sp[7]);
    g4[2] = make_float4(sp[8], 0.f, 0.f, 0.f);
    g4[4] = make_float4(rad[0],  rad[1],  rad[2],  rad[3]);
    g4[5] = make_float4(rad[4],  rad[5],  rad[6],  rad[7]);
    g4[6] = make_float4(rad[8],  rad[9],  rad[10], rad[11]);
    g4[7] = make_float4(rad[12], rad[13], rad[14], rad[15]);
}

// ===========================================================================
// Per-iteration kernel: wave = one dst atom.
//   x layout (non-FIRST in / non-LAST out): channel planes x[c*NS + n*32 + f]
//   FIRST in: compact [n][32] (ch0 only). LAST: fused readout, no xout.
// Blocked half split: half0 = first ceil(cnt/2) edges, half1 = rest.
// Batch-4 gather: 4 sidx loads together, then all <=36 X loads together.
// ===========================================================================
template <bool FIRST, bool LAST>
__global__ __launch_bounds__(256, 4) void iter_kernel(
        const float* __restrict__ xin, float* __restrict__ xout,
        const float* __restrict__ geo2, const int* __restrict__ cur,
        const int* __restrict__ sidx,
        const float* __restrict__ Wbi,
        const float* __restrict__ W1i, const float* __restrict__ b1i,
        const float* __restrict__ W2i, const float* __restrict__ b2i,
        const int* __restrict__ an, const float* __restrict__ posf,
        const float* __restrict__ wc, const void* __restrict__ pos,
        void* __restrict__ out_, int N, int NS) {
    constexpr int NCH = LAST ? 4 : 9;    // channels needed downstream
    constexpr int NR  = LAST ? 2 : 5;    // channel-pair rounds
    __shared__ float sw[1536];           // Wb for this iteration (3x16x32)
    __shared__ float sm[4][9][33];
    bool f32o = false;
    if (LAST) f32o = wave_sniff(pos);    // output dtype flag
    int tid   = threadIdx.x;
    int wslot = tid >> 6;
    int lane  = tid & 63;
    int f     = lane & 31;
    int half  = lane >> 5;
    int n     = blockIdx.x * 4 + wslot;
    bool act  = (n < N);
    float (*tile)[33] = sm[wslot];

    // cooperative Wb -> LDS (frees 48 VGPRs vs register preload)
    for (int i = tid; i < 1536; i += 256) sw[i] = Wbi[i];
    __syncthreads();

    // --- residual x row (own atom): issue EARLY, used after gather ----------
    float xr[9];
    #pragma unroll
    for (int c = 0; c < 9; c++) xr[c] = 0.f;
    if (act) {
        if (FIRST) {
            xr[0] = xin[n * 32 + f];
        } else {
            #pragma unroll
            for (int c = 0; c < NCH; c++) xr[c] = xin[c*NS + n*32 + f];
        }
    }

    // --- gather: blocked halves, batch-4 MLP --------------------------------
    float A0=0.f,A1=0.f,A2=0.f,A3=0.f,A4=0.f,A5=0.f,A6=0.f,A7=0.f,A8=0.f;
    if (act) {
        int cnt = __builtin_amdgcn_readfirstlane(cur[n]);   // wave-uniform
        int h0c = (cnt + 1) >> 1;
        int beg = n * BCAP;
        int b0  = beg + (half ? h0c : 0);
        int myc = half ? (cnt - h0c) : h0c;
        for (int base = 0; base < myc; base += 4) {
            int m = myc - base; if (m > 4) m = 4;
            // batch sidx loads (independent, all in flight together)
            int sA[4];
            #pragma unroll
            for (int j = 0; j < 4; j++)
                sA[j] = (j < m) ? sidx[b0 + base + j] : 0;
            // batch X loads: all <=36 plane loads issue concurrently
            float X[4][9];
            #pragma unroll
            for (int j = 0; j < 4; j++) {
                if (j < m) {
                    if (FIRST) {
                        X[j][0] = xin[sA[j] * 32 + f];
                    } else {
                        #pragma unroll
                        for (int c = 0; c < 9; c++)
                            X[j][c] = xin[c*NS + sA[j]*32 + f];
                    }
                }
            }
            // compute per edge (geo loads independent; compiler pipelines)
            #pragma unroll
            for (int j = 0; j < 4; j++) {
                if (j < m) {
                    int e = b0 + base + j;
                    const float4* gp = (const float4*)(geo2 + (size_t)e * 32);
                    float4 h0v = gp[0], h1v = gp[1], h2v = gp[2];
                    float4 r0 = gp[4], r1 = gp[5], r2 = gp[6], r3 = gp[7];
                    float rad[16] = {r0.x,r0.y,r0.z,r0.w, r1.x,r1.y,r1.z,r1.w,
                                     r2.x,r2.y,r2.z,r2.w, r3.x,r3.y,r3.z,r3.w};
                    float rw0 = 0.f, rw1 = 0.f, rw2 = 0.f;
                    #pragma unroll
                    for (int k = 0; k < 16; k++) {
                        rw0 = fmaf(rad[k], sw[       k*32 + f], rw0);
                        rw1 = fmaf(rad[k], sw[ 512 + k*32 + f], rw1);
                        rw2 = fmaf(rad[k], sw[1024 + k*32 + f], rw2);
                    }
                    float B0 = h0v.x*rw0;
                    float B1 = h0v.y*rw1, B2 = h0v.z*rw1, B3 = h0v.w*rw1;
                    float B4 = h1v.x*rw2, B5 = h1v.y*rw2, B6 = h1v.z*rw2,
                          B7 = h1v.w*rw2, B8 = h2v.x*rw2;
                    if (FIRST) {
                        float k0 = KC0 * X[j][0];
                        A0 += k0*B0; A1 += k0*B1; A2 += k0*B2; A3 += k0*B3;
                        A4 += k0*B4; A5 += k0*B5; A6 += k0*B6; A7 += k0*B7;
                        A8 += k0*B8;
                    } else {
                        float X0=X[j][0],X1=X[j][1],X2=X[j][2],X3=X[j][3],X4=X[j][4],
                              X5=X[j][5],X6=X[j][6],X7=X[j][7],X8=X[j][8];
                        A0 += KC0*(X0*B0 + X1*B1 + X2*B2 + X3*B3 + X4*B4 + X5*B5 + X6*B6 + X7*B7 + X8*B8);
                        A1 += KC0*(X0*B1 + X1*B0) + KG1*(X3*B4 + X4*B3 + X2*B5 + X5*B2)
                            - KG2*(X1*B6 + X6*B1) - KG1*(X1*B8 + X8*B1);
                        A2 += KC0*(X0*B2 + X2*B0) + KG1*(X1*B5 + X5*B1 + X3*B7 + X7*B3)
                            + 2.0f*KG2*(X2*B6 + X6*B2);
                        A3 += KC0*(X0*B3 + X3*B0) + KG1*(X1*B4 + X4*B1 + X2*B7 + X7*B2)
                            - KG2*(X3*B6 + X6*B3) + KG1*(X3*B8 + X8*B3);
                        if (!LAST) {
                            A4 += KC0*(X0*B4 + X4*B0) + KG1*(X1*B3 + X3*B1) + KG5*(X5*B7 + X7*B5)
                                - KG3*(X4*B6 + X6*B4);
                            A5 += KC0*(X0*B5 + X5*B0) + KG1*(X1*B2 + X2*B1) + KG5*(X4*B7 + X7*B4)
                                + KG4*(X5*B6 + X6*B5) - KG5*(X5*B8 + X8*B5);
                            A6 += KC0*(X0*B6 + X6*B0) - KG2*X1*B1 + 2.0f*KG2*X2*B2 - KG2*X3*B3
                                - KG3*X4*B4 + KG4*X5*B5 + KG3*X6*B6 + KG4*X7*B7 - KG3*X8*B8;
                            A7 += KC0*(X0*B7 + X7*B0) + KG1*(X2*B3 + X3*B2) + KG5*(X4*B5 + X5*B4)
                                + KG4*(X6*B7 + X7*B6) + KG5*(X7*B8 + X8*B7);
                            A8 += KC0*(X0*B8 + X8*B0) - KG1*X1*B1 + KG1*X3*B3 - KG5*X5*B5 + KG5*X7*B7
                                - KG3*(X6*B8 + X8*B6);
                        }
                    }
                }
            }
        }
    }
    // combine halves (lane <-> lane^32)
    A0 = xadd32(A0); A1 = xadd32(A1); A2 = xadd32(A2); A3 = xadd32(A3);
    if (!LAST) {
        A4 = xadd32(A4); A5 = xadd32(A5); A6 = xadd32(A6);
        A7 = xadd32(A7); A8 = xadd32(A8);
    }

    // --- stage h = x + msg into wave's LDS tile (f-major) --------------------
    if (act && half == 0) {
        tile[0][f] = xr[0] + A0;
        tile[1][f] = xr[1] + A1;
        tile[2][f] = xr[2] + A2;
        tile[3][f] = xr[3] + A3;
        if (!LAST) {
            tile[4][f] = xr[4] + A4;
            tile[5][f] = xr[5] + A5;
            tile[6][f] = xr[6] + A6;
            tile[7][f] = xr[7] + A7;
            tile[8][f] = xr[8] + A8;
        }
    }
    __syncthreads();

    // --- dense1 + silu: channel-pair rounds, lane = half*32 + g --------------
    int g = f;
    float o1[NR];
    #pragma unroll
    for (int cc = 0; cc < NR; cc++) {
        int c  = cc*2 + half;                  // 0..9 (c==9 invalid group)
        int cs = (c < NCH) ? c : 0;
        int d  = (cs == 0) ? 0 : ((cs < 4) ? 1 : 2);
        const float* W1p = W1i + d * 1024;
        float acc = (c == 0) ? b1i[g] : 0.f;
        #pragma unroll
        for (int fi = 0; fi < 32; fi++)
            acc = fmaf(tile[cs][fi], W1p[fi*32 + g], acc);
        acc = acc * __builtin_amdgcn_rcpf(1.0f + __expf(-acc));  // silu
        o1[cc] = acc;
    }
    __syncthreads();   // dense1 reads complete before tile overwrite
    #pragma unroll
    for (int cc = 0; cc < NR; cc++) {
        int c = cc*2 + half;
        if (c < NCH) tile[c][g] = o1[cc];
    }
    __syncthreads();

    // --- dense2 (+residual); direct plane write-back or fused readout --------
    #pragma unroll
    for (int cc = 0; cc < NR; cc++) {
        int c  = cc*2 + half;
        int cs = (c < NCH) ? c : 0;
        int d  = (cs == 0) ? 0 : ((cs < 4) ? 1 : 2);
        const float* W2p = W2i + d * 1024;
        float acc = (c == 0) ? b2i[g] : 0.f;
        #pragma unroll
        for (int fi = 0; fi < 32; fi++)
            acc = fmaf(tile[cs][fi], W2p[fi*32 + g], acc);
        float xf = xr[cs] + acc;               // new x[n][c][g]
        if (!LAST) {
            if (act && c < 9)
                xout[c*NS + n*32 + g] = xf;    // aligned 128B plane store
        } else if (act) {
            // c in {0,1,2,3}: c==0 -> mono; c>=1 -> dipole channel c-1
            const float* WT = (c == 0) ? (wc + OFF_WT00) : (wc + OFF_WT11);
            float v0 = xf * WT[g*4 + 0];
            float v1 = xf * WT[g*4 + 1];
            float v2 = xf * WT[g*4 + 2];
            float v3 = xf * WT[g*4 + 3];
            #pragma unroll
            for (int m = 1; m <= 16; m <<= 1) {    // reduce within 32-lane half
                v0 += __shfl_xor(v0, m, 64);
                v1 += __shfl_xor(v1, m, 64);
                v2 += __shfl_xor(v2, m, 64);
                v3 += __shfl_xor(v3, m, 64);
            }
            if (g == 0) {
                if (c == 0) {
                    const float* Wmono = wc + OFF_WMONO;
                    float ebv = wc[OFF_EB + an[n]];
                    #pragma unroll
                    for (int m = 0; m < 4; m++) {
                        float a2 = ebv + v0*Wmono[0*4+m] + v1*Wmono[1*4+m]
                                       + v2*Wmono[2*4+m] + v3*Wmono[3*4+m];
                        if (f32o) ((float*)out_)[n*4 + m] = a2;
                        else ((__hip_bfloat16*)out_)[n*4 + m] = __float2bfloat16(a2);
                    }
                } else {
                    float pc = posf[n*3 + (c - 1)];
                    float pv[4] = {v0, v1, v2, v3};
                    #pragma unroll
                    for (int m = 0; m < 4; m++) {
                        float v = pv[m];
                        v = v * __builtin_amdgcn_rcpf(1.0f + __expf(-v));   // silu
                        v = fminf(fmaxf(v, -0.3f), 0.3f);                   // clip
                        v += pc;
                        size_t o = (size_t)N*4 + (size_t)n*12 + (size_t)(c-1)*4 + m;
                        if (f32o) ((float*)out_)[o] = v;
                        else ((__hip_bfloat16*)out_)[o] = __float2bfloat16(v);
                    }
                }
            }
        }
    }
}

// ===========================================================================
// Setup: convert posf/wc + init x ch0 + fill bucket-CSR (sidx + geo2)
// ===========================================================================
__global__ void setup_kernel(const void* pos, const void* Wb, const void* W1,
        const void* b1, const void* W2, const void* b2, const void* Wt00,
        const void* Wt11, const void* Wmono, const void* eb, const void* emb,
        const int* __restrict__ an,
        const int* __restrict__ srcI, const int* __restrict__ dstI,
        float* __restrict__ posf, float* __restrict__ wc,
        float* __restrict__ x, float* __restrict__ geo2, int* __restrict__ cur,
        int* __restrict__ sidx, int N, int E, int use_csr) {
    bool f32 = wave_sniff(pos);
    int i = blockIdx.x * blockDim.x + threadIdx.x;
    int np = N * 3;
    if (i < np) { posf[i] = ldany(pos, i, f32); return; }
    int j = i - np;
    if (j < WC_TOTAL) {
        const void* src; int rel;
        if      (j < OFF_W1)    { src = Wb;    rel = j; }
        else if (j < OFF_B1)    { src = W1;    rel = j - OFF_W1; }
        else if (j < OFF_W2)    { src = b1;    rel = j - OFF_B1; }
        else if (j < OFF_B2)    { src = W2;    rel = j - OFF_W2; }
        else if (j < OFF_WT00)  { src = b2;    rel = j - OFF_B2; }
        else if (j < OFF_WT11)  { src = Wt00;  rel = j - OFF_WT00; }
        else if (j < OFF_WMONO) { src = Wt11;  rel = j - OFF_WT11; }
        else if (j < OFF_EB)    { src = Wmono; rel = j - OFF_WMONO; }
        else if (j < OFF_EMB)   { src = eb;    rel = j - OFF_EB; }
        else                    { src = emb;   rel = j - OFF_EMB; }
        wc[j] = ldany(src, rel, f32);
        return;
    }
    j -= WC_TOTAL;
    if (j < N * 32) {                         // x channel-0 init only
        int n = j >> 5, rem = j & 31;
        size_t o = use_csr ? ((size_t)n * 32 + rem)     // compact x0c
                           : ((size_t)n * 288 + rem);   // legacy slab
        x[o] = ldany(emb, an[n] * 32 + rem, f32);
        return;
    }
    j -= N * 32;
    if (j < E && use_csr) {                   // bucket-CSR fill (raw pos)
        int s = srcI[j], d = dstI[j];
        float sp[9], rad[16];
        if (!edge_geom(ldany(pos, s*3+0, f32) - ldany(pos, d*3+0, f32),
                       ldany(pos, s*3+1, f32) - ldany(pos, d*3+1, f32),
                       ldany(pos, s*3+2, f32) - ldany(pos, d*3+2, f32),
                       sp, rad)) return;
        int slot = atomicAdd(&cur[d], 1);
        sidx[d * BCAP + slot] = s;
        write_geo_slot(geo2 + ((size_t)d * BCAP + slot) * 32, sp, rad);
    }
}

// ===========================================================================
// Fallback (no-CSR) path kernels (legacy [atom][c][f] slab layout)
// ===========================================================================
__global__ void zero_kernel(float4* __restrict__ b, int n) {
    int i = blockIdx.x * blockDim.x + threadIdx.x;
    int stride = gridDim.x * blockDim.x;
    float4 z = make_float4(0.f, 0.f, 0.f, 0.f);
    for (; i < n; i += stride) b[i] = z;
}

__global__ __launch_bounds__(256) void edge_inline_kernel(
        const float* __restrict__ x, float* __restrict__ y,
        const float* __restrict__ posf,
        const int* __restrict__ srcI, const int* __restrict__ dstI,
        const float* __restrict__ Wbi, int E) {
    int f  = threadIdx.x & 31;
    int hw = (blockIdx.x * blockDim.x + threadIdx.x) >> 5;
    int nhw = gridDim.x * (blockDim.x >> 5);
    float w0[16], w1[16], w2[16];
    #pragma unroll
    for (int n = 0; n < 16; n++) {
        w0[n] = Wbi[(0*16 + n)*32 + f];
        w1[n] = Wbi[(1*16 + n)*32 + f];
        w2[n] = Wbi[(2*16 + n)*32 + f];
    }
    for (int e = hw; e < E; e += nhw) {
        int s = srcI[e], d = dstI[e];
        float sp[9], rad[16];
        if (!edge_geom(posf[s*3+0] - posf[d*3+0],
                       posf[s*3+1] - posf[d*3+1],
                       posf[s*3+2] - posf[d*3+2], sp, rad)) continue;
        float rw0 = 0.f, rw1 = 0.f, rw2 = 0.f;
        #pragma unroll
        for (int n = 0; n < 16; n++) {
            rw0 = fmaf(rad[n], w0[n], rw0);
            rw1 = fmaf(rad[n], w1[n], rw1);
            rw2 = fmaf(rad[n], w2[n], rw2);
        }
        float B0 = sp[0]*rw0;
        float B1 = sp[1]*rw1, B2 = sp[2]*rw1, B3 = sp[3]*rw1;
        float B4 = sp[4]*rw2, B5 = sp[5]*rw2, B6 = sp[6]*rw2,
              B7 = sp[7]*rw2, B8 = sp[8]*rw2;
        const float* xp = x + (size_t)s*288 + f;
        float X0 = xp[0],   X1 = xp[32],  X2 = xp[64],  X3 = xp[96],  X4 = xp[128];
        float X5 = xp[160], X6 = xp[192], X7 = xp[224], X8 = xp[256];
        float* yp = y + (size_t)d*288 + f;
        float m;
        m = KC0*(X0*B0 + X1*B1 + X2*B2 + X3*B3 + X4*B4 + X5*B5 + X6*B6 + X7*B7 + X8*B8);
        unsafeAtomicAdd(yp + 0, m);
        m = KC0*(X0*B1 + X1*B0) + KG1*(X3*B4 + X4*B3 + X2*B5 + X5*B2)
          - KG2*(X1*B6 + X6*B1) - KG1*(X1*B8 + X8*B1);
        unsafeAtomicAdd(yp + 32, m);
        m = KC0*(X0*B2 + X2*B0) + KG1*(X1*B5 + X5*B1 + X3*B7 + X7*B3)
          + 2.0f*KG2*(X2*B6 + X6*B2);
        unsafeAtomicAdd(yp + 64, m);
        m = KC0*(X0*B3 + X3*B0) + KG1*(X1*B4 + X4*B1 + X2*B7 + X7*B2)
          - KG2*(X3*B6 + X6*B3) + KG1*(X3*B8 + X8*B3);
        unsafeAtomicAdd(yp + 96, m);
        m = KC0*(X0*B4 + X4*B0) + KG1*(X1*B3 + X3*B1) + KG5*(X5*B7 + X7*B5)
          - KG3*(X4*B6 + X6*B4);
        unsafeAtomicAdd(yp + 128, m);
        m = KC0*(X0*B5 + X5*B0) + KG1*(X1*B2 + X2*B1) + KG5*(X4*B7 + X7*B4)
          + KG4*(X5*B6 + X6*B5) - KG5*(X5*B8 + X8*B5);
        unsafeAtomicAdd(yp + 160, m);
        m = KC0*(X0*B6 + X6*B0) - KG2*X1*B1 + 2.0f*KG2*X2*B2 - KG2*X3*B3
          - KG3*X4*B4 + KG4*X5*B5 + KG3*X6*B6 + KG4*X7*B7 - KG3*X8*B8;
        unsafeAtomicAdd(yp + 192, m);
        m = KC0*(X0*B7 + X7*B0) + KG1*(X2*B3 + X3*B2) + KG5*(X4*B5 + X5*B4)
          + KG4*(X6*B7 + X7*B6) + KG5*(X7*B8 + X8*B7);
        unsafeAtomicAdd(yp + 224, m);
        m = KC0*(X0*B8 + X8*B0) - KG1*X1*B1 + KG1*X3*B3 - KG5*X5*B5 + KG5*X7*B7
          - KG3*(X6*B8 + X8*B6);
        unsafeAtomicAdd(yp + 256, m);
    }
}

__global__ __launch_bounds__(256) void atom_kernel(
        float* __restrict__ x, const float* __restrict__ y,
        const float* __restrict__ W1i, const float* __restrict__ b1i,
        const float* __restrict__ W2i, const float* __restrict__ b2i,
        int N) {
    __shared__ float sm[4][64*33];
    int lane  = threadIdx.x & 63;
    int wslot = threadIdx.x >> 6;
    int u = __builtin_amdgcn_readfirstlane(blockIdx.x * 4 + wslot);
    int t = u / 9;
    int c = u - t * 9;
    int d = (c == 0) ? 0 : ((c < 4) ? 1 : 2);
    const float* W1 = W1i + d * 1024;
    const float* W2 = W2i + d * 1024;
    float* tile = sm[wslot];
    float4 xr4[8];
    #pragma unroll
    for (int k = 0; k < 8; k++) {
        int e  = lane * 4 + k * 256;
        int al = e >> 5, f = e & 31;
        int ag = t * 64 + al;
        float4 s = make_float4(0.f, 0.f, 0.f, 0.f);
        float4 xv = make_float4(0.f, 0.f, 0.f, 0.f);
        if (ag < N) {
            xv = *(const float4*)(x + (size_t)ag * 288 + c * 32 + f);
            float4 yv = *(const float4*)(y + (size_t)ag * 288 + c * 32 + f);
            s = make_float4(xv.x + yv.x, xv.y + yv.y, xv.z + yv.z, xv.w + yv.w);
        }
        xr4[k] = xv;
        *(float4*)(tile + al * 33 + f) = s;
    }
    __syncthreads();
    float yin[32];
    #pragma unroll
    for (int k = 0; k < 8; k++) {
        float4 v = *(const float4*)(tile + lane * 33 + 4 * k);
        yin[4*k+0] = v.x; yin[4*k+1] = v.y; yin[4*k+2] = v.z; yin[4*k+3] = v.w;
    }
    float acc[32];
    #pragma unroll
    for (int g = 0; g < 32; g++) acc[g] = (c == 0) ? b1i[g] : 0.0f;
    #pragma unroll 4
    for (int fi = 0; fi < 32; fi++) {
        float v = yin[fi];
        #pragma unroll
        for (int g = 0; g < 32; g++) acc[g] = fmaf(v, W1[fi*32 + g], acc[g]);
    }
    #pragma unroll
    for (int g = 0; g < 32; g++)
        acc[g] = acc[g] * __builtin_amdgcn_rcpf(1.0f + __expf(-acc[g]));  // silu
    float out[32];
    #pragma unroll
    for (int g = 0; g < 32; g++) out[g] = (c == 0) ? b2i[g] : 0.0f;
    #pragma unroll 4
    for (int fi = 0; fi < 32; fi++) {
        float v = acc[fi];
        #pragma unroll
        for (int g = 0; g < 32; g++) out[g] = fmaf(v, W2[fi*32 + g], out[g]);
    }
    __syncthreads();
    #pragma unroll
    for (int k = 0; k < 8; k++)
        *(float4*)(tile + lane * 33 + 4 * k) =
            make_float4(out[4*k+0], out[4*k+1], out[4*k+2], out[4*k+3]);
    __syncthreads();
    #pragma unroll
    for (int k = 0; k < 8; k++) {
        int e  = lane * 4 + k * 256;
        int al = e >> 5, f = e & 31;
        int ag = t * 64 + al;
        if (ag < N) {
            float4 dv = *(const float4*)(tile + al * 33 + f);
            float4 xv = xr4[k];
            *(float4*)(x + (size_t)ag * 288 + c * 32 + f) =
                make_float4(xv.x + dv.x, xv.y + dv.y, xv.z + dv.z, xv.w + dv.w);
        }
    }
}

__global__ void readout_kernel(const float* __restrict__ x,
        const int* __restrict__ an, const float* __restrict__ posf,
        const float* __restrict__ wc, const void* __restrict__ pos,
        void* __restrict__ out, int N) {
    bool f32 = wave_sniff(pos);
    int n = blockIdx.x * blockDim.x + threadIdx.x;
    if (n >= N) return;
    const float* Wt00  = wc + OFF_WT00;
    const float* Wt11  = wc + OFF_WT11;
    const float* Wmono = wc + OFF_WMONO;
    const float* xb = x + (size_t)n * 288;
    float q[4] = {0.f, 0.f, 0.f, 0.f};
    for (int f = 0; f < 32; f++) {
        float xv = xb[f];
        #pragma unroll
        for (int j = 0; j < 4; j++) q[j] = fmaf(xv, Wt00[f*4 + j], q[j]);
    }
    float ebv = wc[OFF_EB + an[n]];
    #pragma unroll
    for (int m = 0; m < 4; m++) {
        float acc = ebv;
        #pragma unroll
        for (int j = 0; j < 4; j++) acc = fmaf(q[j], Wmono[j*4 + m], acc);
        if (f32) ((float*)out)[n*4 + m] = acc;
        else ((__hip_bfloat16*)out)[n*4 + m] = __float2bfloat16(acc);
    }
    #pragma unroll
    for (int c = 0; c < 3; c++) {
        float pc = posf[n*3 + c];
        const float* xc = xb + (1 + c)*32;
        float dq[4] = {0.f, 0.f, 0.f, 0.f};
        for (int f = 0; f < 32; f++) {
            float xv = xc[f];
            #pragma unroll
            for (int m = 0; m < 4; m++) dq[m] = fmaf(xv, Wt11[f*4 + m], dq[m]);
        }
        #pragma unroll
        for (int m = 0; m < 4; m++) {
            float v = dq[m];
            v = v * __builtin_amdgcn_rcpf(1.0f + __expf(-v));   // silu
            v = fminf(fmaxf(v, -0.3f), 0.3f);                   // clip
            v += pc;
            if (f32) ((float*)out)[N*4 + n*12 + c*4 + m] = v;
            else ((__hip_bfloat16*)out)[N*4 + n*12 + c*4 + m] = __float2bfloat16(v);
        }
    }
}

extern "C" void kernel_launch(void* const* d_in, const int* in_sizes, int n_in,
                              void* d_out, int out_size, void* d_ws, size_t ws_size,
                              hipStream_t stream) {
    const int* an    = (const int*)d_in[0];
    const void* pos  = d_in[1];
    const int* dstI  = (const int*)d_in[2];
    const int* srcI  = (const int*)d_in[3];
    const void* embed= d_in[4];
    const void* Wb   = d_in[5];
    const void* W1   = d_in[6];
    const void* b1   = d_in[7];
    const void* W2   = d_in[8];
    const void* b2   = d_in[9];
    const void* Wt00 = d_in[10];
    const void* Wt11 = d_in[11];
    const void* Wmono= d_in[12];
    const void* eb   = d_in[13];
    int N = in_sizes[0];
    int E = in_sizes[2];
    int NS = N * 32;                          // channel-plane stride

    // --- primary layout: x0c | x1 | x2 | posf | wc | cur | sidx | geo2 ------
    {
        float* x0c  = (float*)d_ws;                       // N*32 (ch0 compact)
        float* x1   = x0c + (size_t)N * 32;               // 9 planes x N*32
        float* x2   = x1 + (size_t)N * 288;               // 9 planes x N*32
        float* posf = x2 + (size_t)N * 288;
        float* wc   = posf + (size_t)N * 3;
        int* cur    = (int*)(wc + WC_TOTAL);              // N
        int* sidx   = cur + N;                            // N*BCAP
        uintptr_t ga = ((uintptr_t)(sidx + (size_t)N * BCAP) + 127) & ~(uintptr_t)127;
        float* geo2 = (float*)ga;                         // N*BCAP*32
        size_t need = (uintptr_t)(geo2 + (size_t)N * BCAP * 32) - (uintptr_t)d_ws;
        if (ws_size >= need) {
            hipMemsetAsync(cur, 0, sizeof(int) * (size_t)N, stream);
            int tot = N * 3 + WC_TOTAL + N * 32 + E;
            setup_kernel<<<(tot + 255)/256, 256, 0, stream>>>(
                pos, Wb, W1, b1, W2, b2, Wt00, Wt11, Wmono, eb, embed,
                an, srcI, dstI, posf, wc, x0c, geo2, cur, sidx, N, E, 1);
            int gblocks = (N + 3) / 4;        // wave per atom
            // iter 0: x0c -> x1
            iter_kernel<true,false><<<gblocks, 256, 0, stream>>>(
                x0c, x1, geo2, cur, sidx,
                wc + OFF_WB, wc + OFF_W1, wc + OFF_B1, wc + OFF_W2, wc + OFF_B2,
                an, posf, wc, pos, d_out, N, NS);
            // iter 1: x1 -> x2
            iter_kernel<false,false><<<gblocks, 256, 0, stream>>>(
                x1, x2, geo2, cur, sidx,
                wc + OFF_WB + 1536, wc + OFF_W1 + 3072, wc + OFF_B1 + 32,
                wc + OFF_W2 + 3072, wc + OFF_B2 + 32,
                an, posf, wc, pos, d_out, N, NS);
            // iter 2 (LAST) + fused readout: x2 -> out
            iter_kernel<false,true><<<gblocks, 256, 0, stream>>>(
                x2, nullptr, geo2, cur, sidx,
                wc + OFF_WB + 3072, wc + OFF_W1 + 6144, wc + OFF_B1 + 64,
                wc + OFF_W2 + 6144, wc + OFF_B2 + 64,
                an, posf, wc, pos, d_out, N, NS);
            return;
        }
    }

    // --- fallback (no-CSR) layout: x | y | posf | wc | cur ------------------
    float* x    = (float*)d_ws;
    float* y    = x + (size_t)N * 288;
    float* posf = y + (size_t)N * 288;
    float* wc   = posf + (size_t)N * 3;
    int* cur    = (int*)(wc + WC_TOTAL);
    int ntiles = (N + 63) / 64;

    hipMemsetAsync(cur, 0, sizeof(int) * (size_t)N, stream);
    zero_kernel<<<512, 256, 0, stream>>>((float4*)x, N * 72);  // zero ch1..8
    {
        int tot = N * 3 + WC_TOTAL + N * 32;
        setup_kernel<<<(tot + 255)/256, 256, 0, stream>>>(
            pos, Wb, W1, b1, W2, b2, Wt00, Wt11, Wmono, eb, embed,
            an, srcI, dstI, posf, wc, x, nullptr, cur, nullptr, N, E, 0);
    }
    int ablocks = (ntiles * 9 + 3) / 4;
    for (int i = 0; i < NITER; i++) {
        zero_kernel<<<512, 256, 0, stream>>>((float4*)y, N * 72);
        edge_inline_kernel<<<2048, 256, 0, stream>>>(x, y, posf, srcI, dstI,
            wc + OFF_WB + (size_t)i*1536, E);
        atom_kernel<<<ablocks, 256, 0, stream>>>(x, y,
            wc + OFF_W1 + (size_t)i*3072, wc + OFF_B1 + (size_t)i*32,
            wc + OFF_W2 + (size_t)i*3072, wc + OFF_B2 + (size_t)i*32, N);
    }
    readout_kernel<<<(N + 255)/256, 256, 0, stream>>>(x, an, posf, wc, pos,
                                                      d_out, N);
}

// Round 8
// 210.072 us; speedup vs baseline: 1.2756x; 1.2756x over previous
//
#include <hip/hip_runtime.h>
#include <hip/hip_bf16.h>

// ---------------------------------------------------------------------------
// MessagePassingModel: N=10000 atoms, E=160000 edges, NC=9 SH channels,
// F=32 features, NB=16 radial basis, NITER=3.
// History: R17 @212 (8 dispatches). R18 coop @972 (grid.sync L2 storm).
// R19 tile-fused @372 (occ 6.6%). R20 @224. R21 @470 (forced spill).
// R22 @236 (sector-misaligned [n][f][12]). R23 @223 (plane SoA, iter=59us,
// VALU 30% / HBM 10% / traffic at compulsory floor). R24 batch-4 @268
// FAILED (scratch writes 152MB/iter).
// R25: R23 + remove block-level coupling. The LDS transpose tile is per-WAVE
// private (sm[wslot]); same-wave LDS write->read needs NO __syncthreads on
// CDNA (DS ops in-order per wave, compiler emits lgkmcnt waits). Deleting
// the 3-4 tile barriers removes the degree-variance convoy (block time was
// max over 4 waves, E[max4 Poisson(2.7)] ~ 2x mean). Only the cooperative
// Wb->LDS load keeps its (cross-wave) barrier. Everything else = R23.
// ---------------------------------------------------------------------------

#define NITER 3
#define BCAP  64      // bucket capacity; post-cutoff dst degree ~Poisson(2.7),
                      // P(>64) ~ 0; dataset fixed -> safe.

// wcvt (fp32 converted weights) layout offsets, in floats
#define OFF_WB    0        // [NITER][3][16][32] = 4608
#define OFF_W1    4608     // [NITER][3][32][32] = 9216
#define OFF_B1    13824    // [NITER][32] = 96
#define OFF_W2    13920    // 9216
#define OFF_B2    23136    // 96
#define OFF_WT00  23232    // [32][4] = 128
#define OFF_WT11  23360    // 128
#define OFF_WMONO 23488    // [4][4] = 16
#define OFF_EB    23504    // 18
#define OFF_EMB   23522    // [18][32] = 576
#define WC_TOTAL  24098

__device__ __forceinline__ float b2f(const __hip_bfloat16 v) { return __bfloat162float(v); }

// Analytic real-Gaunt coefficients for l<=2:
#define KC0 0.28209479177387814f
#define KG1 0.21850968611841584f
#define KG2 0.12615662610100802f
#define KG3 0.18022375157287861f
#define KG4 0.09011187578643931f
#define KG5 0.15607834722743988f

__device__ __forceinline__ float ldany(const void* p, int i, bool f32) {
    return f32 ? ((const float*)p)[i] : b2f(((const __hip_bfloat16*)p)[i]);
}

// Per-wave dtype sniff (fp32-read-as-bf16 -> huge/NaN with ~43%/sample).
__device__ __forceinline__ bool wave_sniff(const void* pos) {
    const __hip_bfloat16* p = (const __hip_bfloat16*)pos;
    int lane = threadIdx.x & 63;
    int bad = 0;
    #pragma unroll
    for (int k = 0; k < 4; k++) {
        float v = b2f(p[lane + k*64]);
        bad |= !(fabsf(v) < 1.0e6f);
    }
    return __ballot(bad) != 0ull;
}

__device__ __forceinline__ float xadd32(float v) {   // v += lane^32 partner
    return v + __int_as_float(__shfl_xor(__float_as_int(v), 32, 64));
}

// --- geometry helper --------------------------------------------------------
__device__ __forceinline__ bool edge_geom(float dx, float dy, float dz,
                                          float* sp, float* rad) {
    float r2 = dx*dx + dy*dy + dz*dz + 1e-12f;
    if (r2 >= 16.0f) return false;
    float r  = sqrtf(r2);
    float t2 = r2 * 0.0625f;
    float fc = __expf(-t2 / (1.0f - t2));
    float u = 1.0f / (1.0f + r);
    float v = 1.0f - u;
    const float BIN[16] = {1.f,15.f,105.f,455.f,1365.f,3003.f,5005.f,6435.f,
                           6435.f,5005.f,3003.f,1365.f,455.f,105.f,15.f,1.f};
    float vp[16];
    vp[0] = 1.0f;
    #pragma unroll
    for (int k = 1; k < 16; k++) vp[k] = vp[k-1] * v;
    float up = 1.0f;
    #pragma unroll
    for (int n = 0; n < 16; n++) { rad[n] = BIN[n] * up * vp[15-n] * fc; up *= u; }
    float ir = 1.0f / r;
    float ux = dx*ir, uy = dy*ir, uz = dz*ir;
    const float c0 = 0.28209479177387814f, c1 = 0.4886025119029199f;
    const float c2a = 1.0925484305920792f, c2b = 0.31539156525252005f, c2c = 0.5462742152960396f;
    sp[0] = c0;
    sp[1] = c1*uy; sp[2] = c1*uz; sp[3] = c1*ux;
    sp[4] = c2a*ux*uy; sp[5] = c2a*uy*uz; sp[6] = c2b*(3.0f*uz*uz - 1.0f);
    sp[7] = c2a*ux*uz; sp[8] = c2c*(ux*ux - uy*uy);
    return true;
}

// --- geo2 slot writer (layout: sph[0..8] pad[9..15] rad[16..31]) ------------
__device__ __forceinline__ void write_geo_slot(float* gp,
                                               const float* sp, const float* rad) {
    float4* g4 = (float4*)gp;                     // geo2 is 128B-aligned
    g4[0] = make_float4(sp[0], sp[1], sp[2], sp[3]);
    g4[1] = make_float4(sp[4], sp[5], sp[6], sp[7]);
    g4[2] = make_float4(sp[8], 0.f, 0.f, 0.f);
    g4[4] = make_float4(rad[0],  rad[1],  rad[2],  rad[3]);
    g4[5] = make_float4(rad[4],  rad[5],  rad[6],  rad[7]);
    g4[6] = make_float4(rad[8],  rad[9],  rad[10], rad[11]);
    g4[7] = make_float4(rad[12], rad[13], rad[14], rad[15]);
}

// ===========================================================================
// Per-iteration kernel: wave = one dst atom.
//   x layout (non-FIRST in / non-LAST out): channel planes x[c*NS + n*32 + f]
//   FIRST in: compact [n][32] (ch0 only). LAST: fused readout, no xout.
// Halves interleave the edge list (e = beg+half, step 2).
// X-row double-buffered: next edge's 9 plane loads issue during compute.
// NO __syncthreads after the Wb load: tile is per-wave private; same-wave
// LDS write->read is ordered by the in-order DS pipeline + lgkmcnt.
// ===========================================================================
template <bool FIRST, bool LAST>
__global__ __launch_bounds__(256, 4) void iter_kernel(
        const float* __restrict__ xin, float* __restrict__ xout,
        const float* __restrict__ geo2, const int* __restrict__ cur,
        const int* __restrict__ sidx,
        const float* __restrict__ Wbi,
        const float* __restrict__ W1i, const float* __restrict__ b1i,
        const float* __restrict__ W2i, const float* __restrict__ b2i,
        const int* __restrict__ an, const float* __restrict__ posf,
        const float* __restrict__ wc, const void* __restrict__ pos,
        void* __restrict__ out_, int N, int NS) {
    constexpr int NCH = LAST ? 4 : 9;    // channels needed downstream
    constexpr int NR  = LAST ? 2 : 5;    // channel-pair rounds
    __shared__ float sw[1536];           // Wb for this iteration (3x16x32)
    __shared__ float sm[4][9][33];
    bool f32o = false;
    if (LAST) f32o = wave_sniff(pos);    // output dtype flag
    int tid   = threadIdx.x;
    int wslot = tid >> 6;
    int lane  = tid & 63;
    int f     = lane & 31;
    int half  = lane >> 5;
    int n     = blockIdx.x * 4 + wslot;
    bool act  = (n < N);
    float (*tile)[33] = sm[wslot];

    // cooperative Wb -> LDS (frees 48 VGPRs vs register preload)
    for (int i = tid; i < 1536; i += 256) sw[i] = Wbi[i];
    __syncthreads();    // the ONLY cross-wave barrier in this kernel

    // --- gather: interleaved halves, X row double-buffered ------------------
    float A0=0.f,A1=0.f,A2=0.f,A3=0.f,A4=0.f,A5=0.f,A6=0.f,A7=0.f,A8=0.f;
    if (act) {
        int cnt = __builtin_amdgcn_readfirstlane(cur[n]);   // wave-uniform
        int beg = n * BCAP;
        int eend = beg + cnt;
        int e = beg + half;
        int s_cur = (e < eend) ? sidx[e] : 0;
        float Xc[9];
        if (FIRST) {
            Xc[0] = xin[s_cur * 32 + f];
        } else {
            #pragma unroll
            for (int c = 0; c < 9; c++) Xc[c] = xin[c*NS + s_cur*32 + f];
        }
        while (e < eend) {
            int e2 = e + 2;
            int s_nxt = (e2 < eend) ? sidx[e2] : 0;
            float Xn[9];                               // issue next row early
            if (FIRST) {
                Xn[0] = xin[s_nxt * 32 + f];
            } else {
                #pragma unroll
                for (int c = 0; c < 9; c++) Xn[c] = xin[c*NS + s_nxt*32 + f];
            }
            // geo2 loads (no dependency) ------------------------------------
            const float4* gp = (const float4*)(geo2 + (size_t)e * 32);
            float4 h0 = gp[0], h1 = gp[1], h2 = gp[2];
            float4 r0 = gp[4], r1 = gp[5], r2 = gp[6], r3 = gp[7];
            float rad[16] = {r0.x,r0.y,r0.z,r0.w, r1.x,r1.y,r1.z,r1.w,
                             r2.x,r2.y,r2.z,r2.w, r3.x,r3.y,r3.z,r3.w};
            float rw0 = 0.f, rw1 = 0.f, rw2 = 0.f;
            #pragma unroll
            for (int k = 0; k < 16; k++) {
                rw0 = fmaf(rad[k], sw[       k*32 + f], rw0);
                rw1 = fmaf(rad[k], sw[ 512 + k*32 + f], rw1);
                rw2 = fmaf(rad[k], sw[1024 + k*32 + f], rw2);
            }
            float B0 = h0.x*rw0;
            float B1 = h0.y*rw1, B2 = h0.z*rw1, B3 = h0.w*rw1;
            float B4 = h1.x*rw2, B5 = h1.y*rw2, B6 = h1.z*rw2,
                  B7 = h1.w*rw2, B8 = h2.x*rw2;
            if (FIRST) {
                float k0 = KC0 * Xc[0];
                A0 += k0*B0; A1 += k0*B1; A2 += k0*B2; A3 += k0*B3; A4 += k0*B4;
                A5 += k0*B5; A6 += k0*B6; A7 += k0*B7; A8 += k0*B8;
            } else {
                float X0=Xc[0],X1=Xc[1],X2=Xc[2],X3=Xc[3],X4=Xc[4],
                      X5=Xc[5],X6=Xc[6],X7=Xc[7],X8=Xc[8];
                A0 += KC0*(X0*B0 + X1*B1 + X2*B2 + X3*B3 + X4*B4 + X5*B5 + X6*B6 + X7*B7 + X8*B8);
                A1 += KC0*(X0*B1 + X1*B0) + KG1*(X3*B4 + X4*B3 + X2*B5 + X5*B2)
                    - KG2*(X1*B6 + X6*B1) - KG1*(X1*B8 + X8*B1);
                A2 += KC0*(X0*B2 + X2*B0) + KG1*(X1*B5 + X5*B1 + X3*B7 + X7*B3)
                    + 2.0f*KG2*(X2*B6 + X6*B2);
                A3 += KC0*(X0*B3 + X3*B0) + KG1*(X1*B4 + X4*B1 + X2*B7 + X7*B2)
                    - KG2*(X3*B6 + X6*B3) + KG1*(X3*B8 + X8*B3);
                if (!LAST) {
                    A4 += KC0*(X0*B4 + X4*B0) + KG1*(X1*B3 + X3*B1) + KG5*(X5*B7 + X7*B5)
                        - KG3*(X4*B6 + X6*B4);
                    A5 += KC0*(X0*B5 + X5*B0) + KG1*(X1*B2 + X2*B1) + KG5*(X4*B7 + X7*B4)
                        + KG4*(X5*B6 + X6*B5) - KG5*(X5*B8 + X8*B5);
                    A6 += KC0*(X0*B6 + X6*B0) - KG2*X1*B1 + 2.0f*KG2*X2*B2 - KG2*X3*B3
                        - KG3*X4*B4 + KG4*X5*B5 + KG3*X6*B6 + KG4*X7*B7 - KG3*X8*B8;
                    A7 += KC0*(X0*B7 + X7*B0) + KG1*(X2*B3 + X3*B2) + KG5*(X4*B5 + X5*B4)
                        + KG4*(X6*B7 + X7*B6) + KG5*(X7*B8 + X8*B7);
                    A8 += KC0*(X0*B8 + X8*B0) - KG1*X1*B1 + KG1*X3*B3 - KG5*X5*B5 + KG5*X7*B7
                        - KG3*(X6*B8 + X8*B6);
                }
            }
            #pragma unroll
            for (int c = 0; c < 9; c++) Xc[c] = Xn[c];
            e = e2; s_cur = s_nxt;
        }
    }
    // combine halves (lane <-> lane^32)
    A0 = xadd32(A0); A1 = xadd32(A1); A2 = xadd32(A2); A3 = xadd32(A3);
    if (!LAST) {
        A4 = xadd32(A4); A5 = xadd32(A5); A6 = xadd32(A6);
        A7 = xadd32(A7); A8 = xadd32(A8);
    }

    // --- residual x row (own atom), lane feature f ---------------------------
    float xr[9];
    #pragma unroll
    for (int c = 0; c < 9; c++) xr[c] = 0.f;
    if (act) {
        if (FIRST) {
            xr[0] = xin[n * 32 + f];
        } else {
            #pragma unroll
            for (int c = 0; c < NCH; c++) xr[c] = xin[c*NS + n*32 + f];
        }
    }

    // --- stage h = x + msg into wave's PRIVATE LDS tile (f-major) ------------
    // No barrier: same-wave DS ops are in-order; compiler emits lgkmcnt waits.
    if (act && half == 0) {
        tile[0][f] = xr[0] + A0;
        tile[1][f] = xr[1] + A1;
        tile[2][f] = xr[2] + A2;
        tile[3][f] = xr[3] + A3;
        if (!LAST) {
            tile[4][f] = xr[4] + A4;
            tile[5][f] = xr[5] + A5;
            tile[6][f] = xr[6] + A6;
            tile[7][f] = xr[7] + A7;
            tile[8][f] = xr[8] + A8;
        }
    }

    // --- dense1 + silu: channel-pair rounds, lane = half*32 + g --------------
    int g = f;
    float o1[NR];
    #pragma unroll
    for (int cc = 0; cc < NR; cc++) {
        int c  = cc*2 + half;                  // 0..9 (c==9 invalid group)
        int cs = (c < NCH) ? c : 0;
        int d  = (cs == 0) ? 0 : ((cs < 4) ? 1 : 2);
        const float* W1p = W1i + d * 1024;
        float acc = (c == 0) ? b1i[g] : 0.f;
        #pragma unroll
        for (int fi = 0; fi < 32; fi++)
            acc = fmaf(tile[cs][fi], W1p[fi*32 + g], acc);
        acc = acc * __builtin_amdgcn_rcpf(1.0f + __expf(-acc));  // silu
        o1[cc] = acc;
    }
    // no barrier (per-wave tile; in-order DS pipeline orders read->write)
    #pragma unroll
    for (int cc = 0; cc < NR; cc++) {
        int c = cc*2 + half;
        if (c < NCH) tile[c][g] = o1[cc];
    }

    // --- dense2 (+residual); direct plane write-back or fused readout --------
    #pragma unroll
    for (int cc = 0; cc < NR; cc++) {
        int c  = cc*2 + half;
        int cs = (c < NCH) ? c : 0;
        int d  = (cs == 0) ? 0 : ((cs < 4) ? 1 : 2);
        const float* W2p = W2i + d * 1024;
        float acc = (c == 0) ? b2i[g] : 0.f;
        #pragma unroll
        for (int fi = 0; fi < 32; fi++)
            acc = fmaf(tile[cs][fi], W2p[fi*32 + g], acc);
        float xf = xr[cs] + acc;               // new x[n][c][g]
        if (!LAST) {
            if (act && c < 9)
                xout[c*NS + n*32 + g] = xf;    // aligned 128B plane store
        } else if (act) {
            // c in {0,1,2,3}: c==0 -> mono; c>=1 -> dipole channel c-1
            const float* WT = (c == 0) ? (wc + OFF_WT00) : (wc + OFF_WT11);
            float v0 = xf * WT[g*4 + 0];
            float v1 = xf * WT[g*4 + 1];
            float v2 = xf * WT[g*4 + 2];
            float v3 = xf * WT[g*4 + 3];
            #pragma unroll
            for (int m = 1; m <= 16; m <<= 1) {    // reduce within 32-lane half
                v0 += __shfl_xor(v0, m, 64);
                v1 += __shfl_xor(v1, m, 64);
                v2 += __shfl_xor(v2, m, 64);
                v3 += __shfl_xor(v3, m, 64);
            }
            if (g == 0) {
                if (c == 0) {
                    const float* Wmono = wc + OFF_WMONO;
                    float ebv = wc[OFF_EB + an[n]];
                    #pragma unroll
                    for (int m = 0; m < 4; m++) {
                        float a2 = ebv + v0*Wmono[0*4+m] + v1*Wmono[1*4+m]
                                       + v2*Wmono[2*4+m] + v3*Wmono[3*4+m];
                        if (f32o) ((float*)out_)[n*4 + m] = a2;
                        else ((__hip_bfloat16*)out_)[n*4 + m] = __float2bfloat16(a2);
                    }
                } else {
                    float pc = posf[n*3 + (c - 1)];
                    float pv[4] = {v0, v1, v2, v3};
                    #pragma unroll
                    for (int m = 0; m < 4; m++) {
                        float v = pv[m];
                        v = v * __builtin_amdgcn_rcpf(1.0f + __expf(-v));   // silu
                        v = fminf(fmaxf(v, -0.3f), 0.3f);                   // clip
                        v += pc;
                        size_t o = (size_t)N*4 + (size_t)n*12 + (size_t)(c-1)*4 + m;
                        if (f32o) ((float*)out_)[o] = v;
                        else ((__hip_bfloat16*)out_)[o] = __float2bfloat16(v);
                    }
                }
            }
        }
    }
}

// ===========================================================================
// Setup: convert posf/wc + init x ch0 + fill bucket-CSR (sidx + geo2)
// ===========================================================================
__global__ void setup_kernel(const void* pos, const void* Wb, const void* W1,
        const void* b1, const void* W2, const void* b2, const void* Wt00,
        const void* Wt11, const void* Wmono, const void* eb, const void* emb,
        const int* __restrict__ an,
        const int* __restrict__ srcI, const int* __restrict__ dstI,
        float* __restrict__ posf, float* __restrict__ wc,
        float* __restrict__ x, float* __restrict__ geo2, int* __restrict__ cur,
        int* __restrict__ sidx, int N, int E, int use_csr) {
    bool f32 = wave_sniff(pos);
    int i = blockIdx.x * blockDim.x + threadIdx.x;
    int np = N * 3;
    if (i < np) { posf[i] = ldany(pos, i, f32); return; }
    int j = i - np;
    if (j < WC_TOTAL) {
        const void* src; int rel;
        if      (j < OFF_W1)    { src = Wb;    rel = j; }
        else if (j < OFF_B1)    { src = W1;    rel = j - OFF_W1; }
        else if (j < OFF_W2)    { src = b1;    rel = j - OFF_B1; }
        else if (j < OFF_B2)    { src = W2;    rel = j - OFF_W2; }
        else if (j < OFF_WT00)  { src = b2;    rel = j - OFF_B2; }
        else if (j < OFF_WT11)  { src = Wt00;  rel = j - OFF_WT00; }
        else if (j < OFF_WMONO) { src = Wt11;  rel = j - OFF_WT11; }
        else if (j < OFF_EB)    { src = Wmono; rel = j - OFF_WMONO; }
        else if (j < OFF_EMB)   { src = eb;    rel = j - OFF_EB; }
        else                    { src = emb;   rel = j - OFF_EMB; }
        wc[j] = ldany(src, rel, f32);
        return;
    }
    j -= WC_TOTAL;
    if (j < N * 32) {                         // x channel-0 init only
        int n = j >> 5, rem = j & 31;
        size_t o = use_csr ? ((size_t)n * 32 + rem)     // compact x0c
                           : ((size_t)n * 288 + rem);   // legacy slab
        x[o] = ldany(emb, an[n] * 32 + rem, f32);
        return;
    }
    j -= N * 32;
    if (j < E && use_csr) {                   // bucket-CSR fill (raw pos)
        int s = srcI[j], d = dstI[j];
        float sp[9], rad[16];
        if (!edge_geom(ldany(pos, s*3+0, f32) - ldany(pos, d*3+0, f32),
                       ldany(pos, s*3+1, f32) - ldany(pos, d*3+1, f32),
                       ldany(pos, s*3+2, f32) - ldany(pos, d*3+2, f32),
                       sp, rad)) return;
        int slot = atomicAdd(&cur[d], 1);
        sidx[d * BCAP + slot] = s;
        write_geo_slot(geo2 + ((size_t)d * BCAP + slot) * 32, sp, rad);
    }
}

// ===========================================================================
// Fallback (no-CSR) path kernels (legacy [atom][c][f] slab layout)
// ===========================================================================
__global__ void zero_kernel(float4* __restrict__ b, int n) {
    int i = blockIdx.x * blockDim.x + threadIdx.x;
    int stride = gridDim.x * blockDim.x;
    float4 z = make_float4(0.f, 0.f, 0.f, 0.f);
    for (; i < n; i += stride) b[i] = z;
}

__global__ __launch_bounds__(256) void edge_inline_kernel(
        const float* __restrict__ x, float* __restrict__ y,
        const float* __restrict__ posf,
        const int* __restrict__ srcI, const int* __restrict__ dstI,
        const float* __restrict__ Wbi, int E) {
    int f  = threadIdx.x & 31;
    int hw = (blockIdx.x * blockDim.x + threadIdx.x) >> 5;
    int nhw = gridDim.x * (blockDim.x >> 5);
    float w0[16], w1[16], w2[16];
    #pragma unroll
    for (int n = 0; n < 16; n++) {
        w0[n] = Wbi[(0*16 + n)*32 + f];
        w1[n] = Wbi[(1*16 + n)*32 + f];
        w2[n] = Wbi[(2*16 + n)*32 + f];
    }
    for (int e = hw; e < E; e += nhw) {
        int s = srcI[e], d = dstI[e];
        float sp[9], rad[16];
        if (!edge_geom(posf[s*3+0] - posf[d*3+0],
                       posf[s*3+1] - posf[d*3+1],
                       posf[s*3+2] - posf[d*3+2], sp, rad)) continue;
        float rw0 = 0.f, rw1 = 0.f, rw2 = 0.f;
        #pragma unroll
        for (int n = 0; n < 16; n++) {
            rw0 = fmaf(rad[n], w0[n], rw0);
            rw1 = fmaf(rad[n], w1[n], rw1);
            rw2 = fmaf(rad[n], w2[n], rw2);
        }
        float B0 = sp[0]*rw0;
        float B1 = sp[1]*rw1, B2 = sp[2]*rw1, B3 = sp[3]*rw1;
        float B4 = sp[4]*rw2, B5 = sp[5]*rw2, B6 = sp[6]*rw2,
              B7 = sp[7]*rw2, B8 = sp[8]*rw2;
        const float* xp = x + (size_t)s*288 + f;
        float X0 = xp[0],   X1 = xp[32],  X2 = xp[64],  X3 = xp[96],  X4 = xp[128];
        float X5 = xp[160], X6 = xp[192], X7 = xp[224], X8 = xp[256];
        float* yp = y + (size_t)d*288 + f;
        float m;
        m = KC0*(X0*B0 + X1*B1 + X2*B2 + X3*B3 + X4*B4 + X5*B5 + X6*B6 + X7*B7 + X8*B8);
        unsafeAtomicAdd(yp + 0, m);
        m = KC0*(X0*B1 + X1*B0) + KG1*(X3*B4 + X4*B3 + X2*B5 + X5*B2)
          - KG2*(X1*B6 + X6*B1) - KG1*(X1*B8 + X8*B1);
        unsafeAtomicAdd(yp + 32, m);
        m = KC0*(X0*B2 + X2*B0) + KG1*(X1*B5 + X5*B1 + X3*B7 + X7*B3)
          + 2.0f*KG2*(X2*B6 + X6*B2);
        unsafeAtomicAdd(yp + 64, m);
        m = KC0*(X0*B3 + X3*B0) + KG1*(X1*B4 + X4*B1 + X2*B7 + X7*B2)
          - KG2*(X3*B6 + X6*B3) + KG1*(X3*B8 + X8*B3);
        unsafeAtomicAdd(yp + 96, m);
        m = KC0*(X0*B4 + X4*B0) + KG1*(X1*B3 + X3*B1) + KG5*(X5*B7 + X7*B5)
          - KG3*(X4*B6 + X6*B4);
        unsafeAtomicAdd(yp + 128, m);
        m = KC0*(X0*B5 + X5*B0) + KG1*(X1*B2 + X2*B1) + KG5*(X4*B7 + X7*B4)
          + KG4*(X5*B6 + X6*B5) - KG5*(X5*B8 + X8*B5);
        unsafeAtomicAdd(yp + 160, m);
        m = KC0*(X0*B6 + X6*B0) - KG2*X1*B1 + 2.0f*KG2*X2*B2 - KG2*X3*B3
          - KG3*X4*B4 + KG4*X5*B5 + KG3*X6*B6 + KG4*X7*B7 - KG3*X8*B8;
        unsafeAtomicAdd(yp + 192, m);
        m = KC0*(X0*B7 + X7*B0) + KG1*(X2*B3 + X3*B2) + KG5*(X4*B5 + X5*B4)
          + KG4*(X6*B7 + X7*B6) + KG5*(X7*B8 + X8*B7);
        unsafeAtomicAdd(yp + 224, m);
        m = KC0*(X0*B8 + X8*B0) - KG1*X1*B1 + KG1*X3*B3 - KG5*X5*B5 + KG5*X7*B7
          - KG3*(X6*B8 + X8*B6);
        unsafeAtomicAdd(yp + 256, m);
    }
}

__global__ __launch_bounds__(256) void atom_kernel(
        float* __restrict__ x, const float* __restrict__ y,
        const float* __restrict__ W1i, const float* __restrict__ b1i,
        const float* __restrict__ W2i, const float* __restrict__ b2i,
        int N) {
    __shared__ float sm[4][64*33];
    int lane  = threadIdx.x & 63;
    int wslot = threadIdx.x >> 6;
    int u = __builtin_amdgcn_readfirstlane(blockIdx.x * 4 + wslot);
    int t = u / 9;
    int c = u - t * 9;
    int d = (c == 0) ? 0 : ((c < 4) ? 1 : 2);
    const float* W1 = W1i + d * 1024;
    const float* W2 = W2i + d * 1024;
    float* tile = sm[wslot];
    float4 xr4[8];
    #pragma unroll
    for (int k = 0; k < 8; k++) {
        int e  = lane * 4 + k * 256;
        int al = e >> 5, f = e & 31;
        int ag = t * 64 + al;
        float4 s = make_float4(0.f, 0.f, 0.f, 0.f);
        float4 xv = make_float4(0.f, 0.f, 0.f, 0.f);
        if (ag < N) {
            xv = *(const float4*)(x + (size_t)ag * 288 + c * 32 + f);
            float4 yv = *(const float4*)(y + (size_t)ag * 288 + c * 32 + f);
            s = make_float4(xv.x + yv.x, xv.y + yv.y, xv.z + yv.z, xv.w + yv.w);
        }
        xr4[k] = xv;
        *(float4*)(tile + al * 33 + f) = s;
    }
    __syncthreads();
    float yin[32];
    #pragma unroll
    for (int k = 0; k < 8; k++) {
        float4 v = *(const float4*)(tile + lane * 33 + 4 * k);
        yin[4*k+0] = v.x; yin[4*k+1] = v.y; yin[4*k+2] = v.z; yin[4*k+3] = v.w;
    }
    float acc[32];
    #pragma unroll
    for (int g = 0; g < 32; g++) acc[g] = (c == 0) ? b1i[g] : 0.0f;
    #pragma unroll 4
    for (int fi = 0; fi < 32; fi++) {
        float v = yin[fi];
        #pragma unroll
        for (int g = 0; g < 32; g++) acc[g] = fmaf(v, W1[fi*32 + g], acc[g]);
    }
    #pragma unroll
    for (int g = 0; g < 32; g++)
        acc[g] = acc[g] * __builtin_amdgcn_rcpf(1.0f + __expf(-acc[g]));  // silu
    float out[32];
    #pragma unroll
    for (int g = 0; g < 32; g++) out[g] = (c == 0) ? b2i[g] : 0.0f;
    #pragma unroll 4
    for (int fi = 0; fi < 32; fi++) {
        float v = acc[fi];
        #pragma unroll
        for (int g = 0; g < 32; g++) out[g] = fmaf(v, W2[fi*32 + g], out[g]);
    }
    __syncthreads();
    #pragma unroll
    for (int k = 0; k < 8; k++)
        *(float4*)(tile + lane * 33 + 4 * k) =
            make_float4(out[4*k+0], out[4*k+1], out[4*k+2], out[4*k+3]);
    __syncthreads();
    #pragma unroll
    for (int k = 0; k < 8; k++) {
        int e  = lane * 4 + k * 256;
        int al = e >> 5, f = e & 31;
        int ag = t * 64 + al;
        if (ag < N) {
            float4 dv = *(const float4*)(tile + al * 33 + f);
            float4 xv = xr4[k];
            *(float4*)(x + (size_t)ag * 288 + c * 32 + f) =
                make_float4(xv.x + dv.x, xv.y + dv.y, xv.z + dv.z, xv.w + dv.w);
        }
    }
}

__global__ void readout_kernel(const float* __restrict__ x,
        const int* __restrict__ an, const float* __restrict__ posf,
        const float* __restrict__ wc, const void* __restrict__ pos,
        void* __restrict__ out, int N) {
    bool f32 = wave_sniff(pos);
    int n = blockIdx.x * blockDim.x + threadIdx.x;
    if (n >= N) return;
    const float* Wt00  = wc + OFF_WT00;
    const float* Wt11  = wc + OFF_WT11;
    const float* Wmono = wc + OFF_WMONO;
    const float* xb = x + (size_t)n * 288;
    float q[4] = {0.f, 0.f, 0.f, 0.f};
    for (int f = 0; f < 32; f++) {
        float xv = xb[f];
        #pragma unroll
        for (int j = 0; j < 4; j++) q[j] = fmaf(xv, Wt00[f*4 + j], q[j]);
    }
    float ebv = wc[OFF_EB + an[n]];
    #pragma unroll
    for (int m = 0; m < 4; m++) {
        float acc = ebv;
        #pragma unroll
        for (int j = 0; j < 4; j++) acc = fmaf(q[j], Wmono[j*4 + m], acc);
        if (f32) ((float*)out)[n*4 + m] = acc;
        else ((__hip_bfloat16*)out)[n*4 + m] = __float2bfloat16(acc);
    }
    #pragma unroll
    for (int c = 0; c < 3; c++) {
        float pc = posf[n*3 + c];
        const float* xc = xb + (1 + c)*32;
        float dq[4] = {0.f, 0.f, 0.f, 0.f};
        for (int f = 0; f < 32; f++) {
            float xv = xc[f];
            #pragma unroll
            for (int m = 0; m < 4; m++) dq[m] = fmaf(xv, Wt11[f*4 + m], dq[m]);
        }
        #pragma unroll
        for (int m = 0; m < 4; m++) {
            float v = dq[m];
            v = v * __builtin_amdgcn_rcpf(1.0f + __expf(-v));   // silu
            v = fminf(fmaxf(v, -0.3f), 0.3f);                   // clip
            v += pc;
            if (f32) ((float*)out)[N*4 + n*12 + c*4 + m] = v;
            else ((__hip_bfloat16*)out)[N*4 + n*12 + c*4 + m] = __float2bfloat16(v);
        }
    }
}

extern "C" void kernel_launch(void* const* d_in, const int* in_sizes, int n_in,
                              void* d_out, int out_size, void* d_ws, size_t ws_size,
                              hipStream_t stream) {
    const int* an    = (const int*)d_in[0];
    const void* pos  = d_in[1];
    const int* dstI  = (const int*)d_in[2];
    const int* srcI  = (const int*)d_in[3];
    const void* embed= d_in[4];
    const void* Wb   = d_in[5];
    const void* W1   = d_in[6];
    const void* b1   = d_in[7];
    const void* W2   = d_in[8];
    const void* b2   = d_in[9];
    const void* Wt00 = d_in[10];
    const void* Wt11 = d_in[11];
    const void* Wmono= d_in[12];
    const void* eb   = d_in[13];
    int N = in_sizes[0];
    int E = in_sizes[2];
    int NS = N * 32;                          // channel-plane stride

    // --- primary layout: x0c | x1 | x2 | posf | wc | cur | sidx | geo2 ------
    {
        float* x0c  = (float*)d_ws;                       // N*32 (ch0 compact)
        float* x1   = x0c + (size_t)N * 32;               // 9 planes x N*32
        float* x2   = x1 + (size_t)N * 288;               // 9 planes x N*32
        float* posf = x2 + (size_t)N * 288;
        float* wc   = posf + (size_t)N * 3;
        int* cur    = (int*)(wc + WC_TOTAL);              // N
        int* sidx   = cur + N;                            // N*BCAP
        uintptr_t ga = ((uintptr_t)(sidx + (size_t)N * BCAP) + 127) & ~(uintptr_t)127;
        float* geo2 = (float*)ga;                         // N*BCAP*32
        size_t need = (uintptr_t)(geo2 + (size_t)N * BCAP * 32) - (uintptr_t)d_ws;
        if (ws_size >= need) {
            hipMemsetAsync(cur, 0, sizeof(int) * (size_t)N, stream);
            int tot = N * 3 + WC_TOTAL + N * 32 + E;
            setup_kernel<<<(tot + 255)/256, 256, 0, stream>>>(
                pos, Wb, W1, b1, W2, b2, Wt00, Wt11, Wmono, eb, embed,
                an, srcI, dstI, posf, wc, x0c, geo2, cur, sidx, N, E, 1);
            int gblocks = (N + 3) / 4;        // wave per atom
            // iter 0: x0c -> x1
            iter_kernel<true,false><<<gblocks, 256, 0, stream>>>(
                x0c, x1, geo2, cur, sidx,
                wc + OFF_WB, wc + OFF_W1, wc + OFF_B1, wc + OFF_W2, wc + OFF_B2,
                an, posf, wc, pos, d_out, N, NS);
            // iter 1: x1 -> x2
            iter_kernel<false,false><<<gblocks, 256, 0, stream>>>(
                x1, x2, geo2, cur, sidx,
                wc + OFF_WB + 1536, wc + OFF_W1 + 3072, wc + OFF_B1 + 32,
                wc + OFF_W2 + 3072, wc + OFF_B2 + 32,
                an, posf, wc, pos, d_out, N, NS);
            // iter 2 (LAST) + fused readout: x2 -> out
            iter_kernel<false,true><<<gblocks, 256, 0, stream>>>(
                x2, nullptr, geo2, cur, sidx,
                wc + OFF_WB + 3072, wc + OFF_W1 + 6144, wc + OFF_B1 + 64,
                wc + OFF_W2 + 6144, wc + OFF_B2 + 64,
                an, posf, wc, pos, d_out, N, NS);
            return;
        }
    }

    // --- fallback (no-CSR) layout: x | y | posf | wc | cur ------------------
    float* x    = (float*)d_ws;
    float* y    = x + (size_t)N * 288;
    float* posf = y + (size_t)N * 288;
    float* wc   = posf + (size_t)N * 3;
    int* cur    = (int*)(wc + WC_TOTAL);
    int ntiles = (N + 63) / 64;

    hipMemsetAsync(cur, 0, sizeof(int) * (size_t)N, stream);
    zero_kernel<<<512, 256, 0, stream>>>((float4*)x, N * 72);  // zero ch1..8
    {
        int tot = N * 3 + WC_TOTAL + N * 32;
        setup_kernel<<<(tot + 255)/256, 256, 0, stream>>>(
            pos, Wb, W1, b1, W2, b2, Wt00, Wt11, Wmono, eb, embed,
            an, srcI, dstI, posf, wc, x, nullptr, cur, nullptr, N, E, 0);
    }
    int ablocks = (ntiles * 9 + 3) / 4;
    for (int i = 0; i < NITER; i++) {
        zero_kernel<<<512, 256, 0, stream>>>((float4*)y, N * 72);
        edge_inline_kernel<<<2048, 256, 0, stream>>>(x, y, posf, srcI, dstI,
            wc + OFF_WB + (size_t)i*1536, E);
        atom_kernel<<<ablocks, 256, 0, stream>>>(x, y,
            wc + OFF_W1 + (size_t)i*3072, wc + OFF_B1 + (size_t)i*32,
            wc + OFF_W2 + (size_t)i*3072, wc + OFF_B2 + (size_t)i*32, N);
    }
    readout_kernel<<<(N + 255)/256, 256, 0, stream>>>(x, an, posf, wc, pos,
                                                      d_out, N);
}